// Round 7
// baseline (325.962 us; speedup 1.0000x reference)
//
#include <hip/hip_runtime.h>
#include <hip/hip_bf16.h>

typedef __hip_bfloat16 bf16;
typedef short bf16x8 __attribute__((ext_vector_type(8)));   // 8 bf16 = 4 VGPRs
typedef float f32x4 __attribute__((ext_vector_type(4)));    // C/D frag

#define D_MODEL 1024
#define SEQ     2048
#define NHEAD   16
#define DHEAD   64
#define BATCH   2
#define MROWS   (BATCH*SEQ)   // 4096
#define LOG2E   1.4426950408889634f

// async global->LDS, 16B per lane (m97 lever). Dest = wave-uniform base +
// lane*16 (m104/m108) — all call sites satisfy this.
__device__ __forceinline__ void lds_dma16(const bf16* g, bf16* l) {
  __builtin_amdgcn_global_load_lds(
      (const __attribute__((address_space(1))) void*)g,
      (__attribute__((address_space(3))) void*)l, 16, 0, 0);
}

__device__ __forceinline__ uint4 pack8_f32(const float4 x0, const float4 x1) {
  union { uint4 q; bf16 h[8]; } pk;
  pk.h[0]=__float2bfloat16(x0.x); pk.h[1]=__float2bfloat16(x0.y);
  pk.h[2]=__float2bfloat16(x0.z); pk.h[3]=__float2bfloat16(x0.w);
  pk.h[4]=__float2bfloat16(x1.x); pk.h[5]=__float2bfloat16(x1.y);
  pk.h[6]=__float2bfloat16(x1.z); pk.h[7]=__float2bfloat16(x1.w);
  return pk.q;
}

// ---------------------------------------------------------------------------
// Convert the 4 weight matrices fp32 -> bf16 (8.39 MB into ws). grid (128,4).
// ---------------------------------------------------------------------------
__global__ __launch_bounds__(256) void conv_w(
    const float* s0, const float* s1, const float* s2, const float* s3,
    bf16* d0, bf16* d1, bf16* d2, bf16* d3)
{
  const float* S[4] = {s0,s1,s2,s3};
  bf16*        D[4] = {d0,d1,d2,d3};
  const int z = blockIdx.y;
  const int n8 = D_MODEL*D_MODEL/8;
  for (int i = blockIdx.x*256 + threadIdx.x; i < n8; i += 128*256) {
    float4 a = ((const float4*)S[z])[2*i];
    float4 b = ((const float4*)S[z])[2*i+1];
    ((uint4*)D[z])[i] = pack8_f32(a, b);
  }
}

// ---------------------------------------------------------------------------
// Fused QKV projection, hybrid staging, BK=64, 128x128 tile, grid (8,32,3).
// W (bf16, pre-converted, the reused operand) via global_load_lds DMA;
// A (fp32 input) staged with fused fp32->bf16 pack (vector loads).
// z<2 (Q,K): SWAPPED mfma(wf,af) -> lane holds 4 consecutive output columns
// -> 8B packed epilogue stores. z=0 folds 0.125*log2e into output.
// z=2 (V): unswapped, written TRANSPOSED VpT[(b*1024+c)*SEQ + s].
// ---------------------------------------------------------------------------
__global__ __launch_bounds__(256) void gemm_qkv(
    const float* A0, const float* A1, const float* A2,
    const bf16* W0, const bf16* W1, const bf16* W2,
    const float* B0, const float* B1, const float* B2,
    bf16* C0, bf16* C1, bf16* VpT)
{
  __shared__ __align__(16) bf16 As[8*128*8];   // 16 KB
  __shared__ __align__(16) bf16 Ws[8*128*8];   // 16 KB
  const int z = blockIdx.z;
  const float* A = (z == 0) ? A0 : (z == 1) ? A1 : A2;
  const bf16*  W = (z == 0) ? W0 : (z == 1) ? W1 : W2;
  const float* Bv = (z == 0) ? B0 : (z == 1) ? B1 : B2;
  const bool swapped = (z < 2);
  const int K = D_MODEL, N = D_MODEL;
  const int tid  = threadIdx.x;
  const int lane = tid & 63, wave = tid >> 6;
  const int wm   = wave >> 1, wn = wave & 1;
  const int quad = lane >> 4, l16 = lane & 15;
  const int row0 = blockIdx.y * 128, col0 = blockIdx.x * 128;

  const f32x4 zero = {0.f, 0.f, 0.f, 0.f};
  f32x4 acc[4][4];
  #pragma unroll
  for (int i = 0; i < 4; ++i)
    #pragma unroll
    for (int j = 0; j < 4; ++j) acc[i][j] = zero;

  for (int k0 = 0; k0 < K; k0 += 64) {
    __syncthreads();
    // W first (async DMA in flight while we pack A)
    #pragma unroll
    for (int t = 0; t < 4; ++t) {
      int s = t*256 + tid;
      int g = s >> 7, r = s & 127;
      lds_dma16(W + (size_t)(col0 + r)*K + k0 + g*8, &Ws[s*8]);
    }
    #pragma unroll
    for (int t = 0; t < 4; ++t) {
      int s = t*256 + tid;
      int g = s >> 7, r = s & 127;
      const float* Af = A + (size_t)(row0 + r)*K + k0 + g*8;
      *(uint4*)&As[s*8] = pack8_f32(((const float4*)Af)[0], ((const float4*)Af)[1]);
    }
    __syncthreads();
    #pragma unroll
    for (int ks = 0; ks < 2; ++ks) {
      bf16x8 af[4], wf[4];
      #pragma unroll
      for (int mt = 0; mt < 4; ++mt)
        af[mt] = *(const bf16x8*)&As[((ks*4 + quad)*128 + wm*64 + mt*16 + l16)*8];
      #pragma unroll
      for (int nt = 0; nt < 4; ++nt)
        wf[nt] = *(const bf16x8*)&Ws[((ks*4 + quad)*128 + wn*64 + nt*16 + l16)*8];
      if (swapped) {
        #pragma unroll
        for (int mt = 0; mt < 4; ++mt)
          #pragma unroll
          for (int nt = 0; nt < 4; ++nt)
            acc[mt][nt] = __builtin_amdgcn_mfma_f32_16x16x32_bf16(wf[nt], af[mt], acc[mt][nt], 0, 0, 0);
      } else {
        #pragma unroll
        for (int mt = 0; mt < 4; ++mt)
          #pragma unroll
          for (int nt = 0; nt < 4; ++nt)
            acc[mt][nt] = __builtin_amdgcn_mfma_f32_16x16x32_bf16(af[mt], wf[nt], acc[mt][nt], 0, 0, 0);
      }
    }
  }

  if (swapped) {
    bf16* C = (z == 0) ? C0 : C1;
    const float scale = (z == 0) ? 0.125f*LOG2E : 1.0f;
    #pragma unroll
    for (int mt = 0; mt < 4; ++mt) {
      int r = row0 + wm*64 + mt*16 + l16;
      #pragma unroll
      for (int nt = 0; nt < 4; ++nt) {
        int c0 = col0 + wn*64 + nt*16 + quad*4;
        float4 b4 = *(const float4*)(Bv + c0);
        union { uint2 u; bf16 h[4]; } pk;
        pk.h[0] = __float2bfloat16((acc[mt][nt][0] + b4.x) * scale);
        pk.h[1] = __float2bfloat16((acc[mt][nt][1] + b4.y) * scale);
        pk.h[2] = __float2bfloat16((acc[mt][nt][2] + b4.z) * scale);
        pk.h[3] = __float2bfloat16((acc[mt][nt][3] + b4.w) * scale);
        *(uint2*)&C[(size_t)r*N + c0] = pk.u;
      }
    }
  } else {
    const int bb = row0 >> 11;
    const int sbase = (row0 & 2047) + wm*64;
    #pragma unroll
    for (int nt = 0; nt < 4; ++nt) {
      int c = col0 + wn*64 + nt*16 + l16;
      float bv = Bv[c];
      bf16* col = VpT + (size_t)((bb << 10) + c) * SEQ;
      #pragma unroll
      for (int mt = 0; mt < 4; ++mt) {
        int s = sbase + mt*16 + quad*4;
        union { uint2 u; bf16 h[4]; } pk;
        #pragma unroll
        for (int j = 0; j < 4; ++j) pk.h[j] = __float2bfloat16(acc[mt][nt][j] + bv);
        *(uint2*)(col + s) = pk.u;
      }
    }
  }
}

// ---------------------------------------------------------------------------
// Output projection: both operands bf16 via DMA, BK=64, 128x64 tile,
// swapped mfma -> float4 16B stores to fp32 d_out. grid (16,32).
// ---------------------------------------------------------------------------
__global__ __launch_bounds__(256) void gemm_out_dma(
    const bf16* __restrict__ A, const bf16* __restrict__ W,
    const float* __restrict__ Bv, float* __restrict__ C)
{
  __shared__ __align__(16) bf16 As[8*128*8];   // 16 KB
  __shared__ __align__(16) bf16 Ws[8*64*8];    // 8 KB
  const int K = D_MODEL, N = D_MODEL;
  const int tid  = threadIdx.x;
  const int lane = tid & 63, wave = tid >> 6;
  const int wm   = wave >> 1, wn = wave & 1;
  const int quad = lane >> 4, l16 = lane & 15;
  const int row0 = blockIdx.y * 128, col0 = blockIdx.x * 64;

  const f32x4 zero = {0.f, 0.f, 0.f, 0.f};
  f32x4 acc[4][2];
  #pragma unroll
  for (int i = 0; i < 4; ++i)
    #pragma unroll
    for (int j = 0; j < 2; ++j) acc[i][j] = zero;

  for (int k0 = 0; k0 < K; k0 += 64) {
    __syncthreads();
    #pragma unroll
    for (int t = 0; t < 4; ++t) {
      int s = t*256 + tid;
      int g = s >> 7, r = s & 127;
      lds_dma16(A + (size_t)(row0 + r)*K + k0 + g*8, &As[s*8]);
    }
    #pragma unroll
    for (int t = 0; t < 2; ++t) {
      int s = t*256 + tid;
      int g = s >> 6, r = s & 63;
      lds_dma16(W + (size_t)(col0 + r)*K + k0 + g*8, &Ws[s*8]);
    }
    __syncthreads();
    #pragma unroll
    for (int ks = 0; ks < 2; ++ks) {
      bf16x8 af[4], wf[2];
      #pragma unroll
      for (int mt = 0; mt < 4; ++mt)
        af[mt] = *(const bf16x8*)&As[((ks*4 + quad)*128 + wm*64 + mt*16 + l16)*8];
      #pragma unroll
      for (int nt = 0; nt < 2; ++nt)
        wf[nt] = *(const bf16x8*)&Ws[((ks*4 + quad)*64 + wn*32 + nt*16 + l16)*8];
      #pragma unroll
      for (int mt = 0; mt < 4; ++mt)
        #pragma unroll
        for (int nt = 0; nt < 2; ++nt)
          acc[mt][nt] = __builtin_amdgcn_mfma_f32_16x16x32_bf16(wf[nt], af[mt], acc[mt][nt], 0, 0, 0);
    }
  }

  #pragma unroll
  for (int mt = 0; mt < 4; ++mt) {
    int r = row0 + wm*64 + mt*16 + l16;
    #pragma unroll
    for (int nt = 0; nt < 2; ++nt) {
      int c0 = col0 + wn*32 + nt*16 + quad*4;
      float4 b4 = *(const float4*)(Bv + c0);
      float4 o;
      o.x = acc[mt][nt][0] + b4.x; o.y = acc[mt][nt][1] + b4.y;
      o.z = acc[mt][nt][2] + b4.z; o.w = acc[mt][nt][3] + b4.w;
      *(float4*)&C[(size_t)r*N + c0] = o;
    }
  }
}

// ---------------------------------------------------------------------------
// Flash attention (unchanged from round 6): 512 threads, q-tile 128,
// K-tile 128, S^T = K Q^T, O^T = V^T P^T, log2-domain softmax,
// V-tile register prefetch one tile ahead.
// ---------------------------------------------------------------------------
__global__ __launch_bounds__(512) void attn_fused(
    const bf16* __restrict__ Qp, const bf16* __restrict__ Kp,
    const bf16* __restrict__ VpT, bf16* __restrict__ Ao)
{
  __shared__ __align__(16) bf16 UN[128*128];    // 32 KB: Qs staging then Ps
  __shared__ __align__(16) bf16 Ks[8*128*8];    // 16 KB
  __shared__ __align__(16) bf16 Vt[64*16*8];    // 16 KB  V^T swizzled

  const int tid  = threadIdx.x;
  const int lane = tid & 63, wave = tid >> 6;
  const int quad = lane >> 4, l16 = lane & 15;
  const int qt = blockIdx.x, h = blockIdx.y, b = blockIdx.z;
  const int q0 = qt * 128;
  const bf16* Qb = Qp + ((size_t)b*SEQ + q0)*D_MODEL + h*DHEAD;
  const bf16* Kb = Kp + (size_t)b*SEQ*D_MODEL + h*DHEAD;
  const bf16* Vg = VpT + (size_t)((b << 10) + h*DHEAD) * SEQ;

  #pragma unroll
  for (int t = 0; t < 2; ++t) {
    int s = t*512 + tid;
    int g = s >> 7, r = s & 127;
    lds_dma16(Qb + (size_t)r*D_MODEL + g*8, &UN[s*8]);
  }
  __syncthreads();

  const int wq0 = wave * 16;
  const int q   = wq0 + l16;
  bf16x8 qa[2];
  #pragma unroll
  for (int ks = 0; ks < 2; ++ks)
    qa[ks] = *(const bf16x8*)&UN[((ks*4 + quad)*128 + q)*8];
  bf16* Ps = UN;
  const int swz = (l16 & 7) << 1;

  const int vn0 = tid >> 4,        vgk0 = tid & 15;
  const int vn1 = (512+tid) >> 4,  vgk1 = (512+tid) & 15;
  const int vsw0 = (vgk0 + vn0 + (vn0 >> 3)) & 15;
  const int vsw1 = (vgk1 + vn1 + (vn1 >> 3)) & 15;
  uint4 vreg0 = *(const uint4*)(Vg + (size_t)vn0*SEQ + vgk0*8);
  uint4 vreg1 = *(const uint4*)(Vg + (size_t)vn1*SEQ + vgk1*8);

  const f32x4 zero = {0.f, 0.f, 0.f, 0.f};
  f32x4 acc_o[4];
  #pragma unroll
  for (int dt = 0; dt < 4; ++dt) acc_o[dt] = zero;
  float m_s = -1e30f, l_s = 0.f;

  for (int kt = 0; kt < SEQ/128; ++kt) {
    __syncthreads();
    #pragma unroll
    for (int t = 0; t < 2; ++t) {
      int s = t*512 + tid;
      int g = s >> 7, kk = s & 127;
      lds_dma16(Kb + (size_t)(kt*128 + kk)*D_MODEL + g*8, &Ks[s*8]);
    }
    *(uint4*)&Vt[(vn0*16 + vsw0)*8] = vreg0;
    *(uint4*)&Vt[(vn1*16 + vsw1)*8] = vreg1;
    {
      int ktn = (kt + 1 < SEQ/128) ? kt + 1 : kt;
      vreg0 = *(const uint4*)(Vg + (size_t)vn0*SEQ + ktn*128 + vgk0*8);
      vreg1 = *(const uint4*)(Vg + (size_t)vn1*SEQ + ktn*128 + vgk1*8);
    }
    __syncthreads();

    f32x4 sc[8];
    #pragma unroll
    for (int kt2 = 0; kt2 < 8; ++kt2) sc[kt2] = zero;
    #pragma unroll
    for (int ks = 0; ks < 2; ++ks) {
      bf16x8 kf[8];
      #pragma unroll
      for (int kt2 = 0; kt2 < 8; ++kt2)
        kf[kt2] = *(const bf16x8*)&Ks[((ks*4 + quad)*128 + kt2*16 + l16)*8];
      #pragma unroll
      for (int kt2 = 0; kt2 < 8; ++kt2)
        sc[kt2] = __builtin_amdgcn_mfma_f32_16x16x32_bf16(kf[kt2], qa[ks], sc[kt2], 0, 0, 0);
    }

    float vmax = -1e30f;
    #pragma unroll
    for (int kt2 = 0; kt2 < 8; ++kt2) {
      f32x4 s4 = sc[kt2];
      vmax = fmaxf(vmax, fmaxf(fmaxf(s4[0], s4[1]), fmaxf(s4[2], s4[3])));
    }
    vmax = fmaxf(vmax, __shfl_xor(vmax, 16));
    vmax = fmaxf(vmax, __shfl_xor(vmax, 32));
    float mnew  = fmaxf(m_s, vmax);
    float alpha = __builtin_amdgcn_exp2f(m_s - mnew);
    float rs = 0.f;
    #pragma unroll
    for (int kt2 = 0; kt2 < 8; ++kt2) {
      float p0 = __builtin_amdgcn_exp2f(sc[kt2][0] - mnew);
      float p1 = __builtin_amdgcn_exp2f(sc[kt2][1] - mnew);
      float p2 = __builtin_amdgcn_exp2f(sc[kt2][2] - mnew);
      float p3 = __builtin_amdgcn_exp2f(sc[kt2][3] - mnew);
      rs += (p0 + p1) + (p2 + p3);
      union { uint2 u; bf16 hh[4]; } pk;
      pk.hh[0] = __float2bfloat16(p0); pk.hh[1] = __float2bfloat16(p1);
      pk.hh[2] = __float2bfloat16(p2); pk.hh[3] = __float2bfloat16(p3);
      int phys = (kt2*4 + quad) ^ swz;
      *(uint2*)&Ps[q*128 + phys*4] = pk.u;
    }
    rs += __shfl_xor(rs, 16);
    rs += __shfl_xor(rs, 32);
    l_s = l_s*alpha + rs;
    m_s = mnew;
    #pragma unroll
    for (int dt = 0; dt < 4; ++dt) acc_o[dt] = acc_o[dt] * alpha;

    #pragma unroll
    for (int ks2 = 0; ks2 < 4; ++ks2) {
      bf16x8 vf[4], pa;
      #pragma unroll
      for (int dt = 0; dt < 4; ++dt) {
        int n = dt*16 + l16;
        int sw = (ks2*4 + quad + n + (n >> 3)) & 15;
        vf[dt] = *(const bf16x8*)&Vt[(n*16 + sw)*8];
      }
      int phys = (ks2*8 + quad*2) ^ swz;
      pa = *(const bf16x8*)&Ps[q*128 + phys*4];
      #pragma unroll
      for (int dt = 0; dt < 4; ++dt)
        acc_o[dt] = __builtin_amdgcn_mfma_f32_16x16x32_bf16(vf[dt], pa, acc_o[dt], 0, 0, 0);
    }
  }

  bf16* Ob = Ao + ((size_t)b*SEQ + q0)*D_MODEL + h*DHEAD;
  float inv = 1.f / l_s;
  #pragma unroll
  for (int dt = 0; dt < 4; ++dt) {
    union { uint2 u; bf16 hh[4]; } pk;
    #pragma unroll
    for (int j = 0; j < 4; ++j) pk.hh[j] = __float2bfloat16(acc_o[dt][j] * inv);
    *(uint2*)(Ob + (size_t)q*D_MODEL + dt*16 + quad*4) = pk.u;
  }
}

// ---------------------------------------------------------------------------
extern "C" void kernel_launch(void* const* d_in, const int* in_sizes, int n_in,
                              void* d_out, int out_size, void* d_ws, size_t ws_size,
                              hipStream_t stream) {
  const float* q   = (const float*)d_in[0];
  const float* k   = (const float*)d_in[1];
  const float* v   = (const float*)d_in[2];
  const float* w_q = (const float*)d_in[3];
  const float* b_q = (const float*)d_in[4];
  const float* w_k = (const float*)d_in[5];
  const float* b_k = (const float*)d_in[6];
  const float* w_v = (const float*)d_in[7];
  const float* b_v = (const float*)d_in[8];
  const float* w_o = (const float*)d_in[9];
  const float* b_o = (const float*)d_in[10];

  const size_t nbuf = (size_t)MROWS * D_MODEL;    // 4.19M elems
  const size_t wbuf = (size_t)D_MODEL * D_MODEL;  // 1.05M elems

  // ws layout (16.78 MB total — within the proven >=16.78 MB floor):
  bf16* wqc = (bf16*)d_ws;
  bf16* wkc = wqc + wbuf;
  bf16* wvc = wkc + wbuf;
  bf16* woc = wvc + wbuf;
  bf16* Qp  = woc + wbuf;
  bf16* Ao  = Qp;                                 // alias: block-local slices
  // d_out (fp32, 16.78 MB) doubles as scratch until the final GEMM:
  bf16* Kp  = (bf16*)d_out;
  bf16* VpT = Kp + nbuf;

  conv_w<<<dim3(128,4), 256, 0, stream>>>(w_q, w_k, w_v, w_o,
                                          wqc, wkc, wvc, woc);
  gemm_qkv<<<dim3(8,32,3), 256, 0, stream>>>(q, k, v, wqc, wkc, wvc,
                                             b_q, b_k, b_v, Qp, Kp, VpT);
  attn_fused<<<dim3(16,16,2), 512, 0, stream>>>(Qp, Kp, VpT, Ao);
  gemm_out_dma<<<dim3(16,32), 256, 0, stream>>>(Ao, woc, b_o, (float*)d_out);
}